// Round 13
// baseline (641.426 us; speedup 1.0000x reference)
//
#include <hip/hip_runtime.h>

// MemoryBank contrastive loss, steady state.
// B=1024, D=128, C=50, K=4096, N = C*K = 204800. TEMP=0.3.
// loss = (1/B) * sum_b w_b * ( ln(sum exp(dot/T)) - dot_pos/T )
// SCALE = log2(e)/T folded into normalized bf16 features: MFMA acc feeds exp2.
//
// R17: barrier-free gemm via operand swap. R16 proved the ~110us non-kernel
// time is FIXED per-iteration (1 vs 3 launches ~ same overhead) -> only
// kernel-time matters; fusion also poisoned the gemm (190us) -> revert to
// 3 kernels. R7's 78.6 = 2x max pipe (LDS 39, MFMA 26, trans ~20) because
// per-tile __syncthreads locksteps all waves into phase-serial execution.
// Restructure: features are tile-INVARIANT -> stage the block's 256 feat
// rows in LDS ONCE (64KB bf16 frag-linear, read-only after 1 init barrier)
// and stream memory rows through registers as the A-operand. Each wave owns
// its own n-rows: no cross-wave sharing, no staging, no dbuf, NO BARRIERS
// in the main loop -- 16 free-running waves/CU hide all latency. MFMA usage
// is the verified one with roles swapped: both operands gather as
// lane L <- X[dim16=L&15][k=(L>>4)*8+j]; C-col(L&15)=feat-m (per-m sums
// lane-local), C-row(quad*4+reg)=mem-n (3 adds + shfl_xor 16,32).
// LDS reads halve (0.82GB ~16us), writes ~0; MFMA 26us = top pipe.
// S via 1KB LDS reduce (128x less atomic contention). Grid (128,4) proven
// dedupe; 512thr; launch_bounds(512,4); regs ~105 (A-frag only 16 vs
// mf=4's 64 -> R15's spill mode doesn't apply). 100 n-tiles/xc, 13/12 per
// wave. Checks: VGPR 100-115 + WRITE ~2MB (no spill), MfmaUtil 45-70%,
// dur 38-55us. Occ ~19 would mean 66KB LDS dropped residency to 1 blk/CU.

#define LN2f 0.6931471805599453f
#define SCALEf 4.808983469629878f   // log2(e)/0.3

typedef __attribute__((ext_vector_type(8))) short bf16x8;
typedef __attribute__((ext_vector_type(4))) float f32x4;
typedef unsigned int u32;

__device__ __forceinline__ unsigned short f2bf(float x) {
    union { float f; unsigned int u; } c; c.f = x;
    unsigned int u = c.u;
    u = (u + 0x7fffu + ((u >> 16) & 1u)) >> 16;   // RNE (features only)
    return (unsigned short)u;
}
__device__ __forceinline__ float bf2f(unsigned short h) {
    union { unsigned int u; float f; } c; c.u = ((unsigned int)h) << 16;
    return c.f;
}
// two fp32 -> two bf16 (truncation) in one v_perm_b32: [bf(lo) | bf(hi)<<16]
__device__ __forceinline__ unsigned int pack_bf2(float lo, float hi) {
    union { float f; unsigned int u; } a, b; a.f = lo; b.f = hi;
    return __builtin_amdgcn_perm(b.u, a.u, 0x07060302u);
}

// ---- Kernel 1: normalize+scale features -> bf16; zero S and out -------------
__global__ void normalize_feat(const float* __restrict__ f,
                               unsigned short* __restrict__ featb,
                               float* __restrict__ S,
                               float* __restrict__ out) {
    const int b = blockIdx.x;          // 1024 blocks
    const int t = threadIdx.x;         // 128 threads
    if (t == 0) S[b] = 0.0f;
    if (b == 0 && t == 1) *out = 0.0f;
    float v = f[b * 128 + t];
    float ss = v * v;
    #pragma unroll
    for (int m = 1; m < 64; m <<= 1) ss += __shfl_xor(ss, m, 64);
    __shared__ float wsum[2];
    if ((t & 63) == 0) wsum[t >> 6] = ss;
    __syncthreads();
    float tot = wsum[0] + wsum[1];
    float inv = SCALEf / fmaxf(sqrtf(tot), 1e-12f);
    featb[b * 128 + t] = f2bf(v * inv);
}

// ---- Kernel 2: barrier-free fused GEMM + exp2-sum ---------------------------
// 512 thr = 8 waves. Block: 256 feat rows (LDS, persistent) x 1600 mem rows
// (streamed). Wave owns n-tiles of 16 mem rows; per tile: 64 MFMA against
// all 16 feat m-frags; exp2 + n-reduce; accumulate per-m into s_part.
__global__ __launch_bounds__(512, 4) void gemm_lse(
        const unsigned short* __restrict__ featb,  // [1024][128] bf16 (scaled)
        const float* __restrict__ mem,             // [204800][128] fp32
        float* __restrict__ S)                     // [1024] exp2-sums
{
    // feat fragments: slot (mf*4+ks)*64 + L holds
    // featb[m_base + mf*16 + (L&15)][k = ks*32 + (L>>4)*8 .. +8]  (16 B)
    __shared__ uint4 fLDS[4096];      // 64 KB, read-only after init
    __shared__ float S_lds[256];      // per-block S accumulator

    const int tid  = threadIdx.x;
    const int wave = tid >> 6;        // 0..7
    const int lane = tid & 63;
    const int c    = lane & 15;
    const int quad = lane >> 4;

    const int m_base = blockIdx.y * 256;
    const int xc     = blockIdx.x;    // 0..127; owns n-rows [xc*1600, +1600)

    if (tid < 256) S_lds[tid] = 0.0f;

    // init: featb (bf16, row-major) -> fragment-linear LDS, 8 slots/thread
    #pragma unroll
    for (int i = 0; i < 8; ++i) {
        int s  = i * 512 + tid;           // slot 0..4095
        int mf = s >> 8, ks = (s >> 6) & 3, L = s & 63;
        int row = m_base + mf * 16 + (L & 15);
        fLDS[s] = *(const uint4*)((const char*)featb
                                  + (size_t)row * 256 + ks * 64 + (L >> 4) * 16);
    }
    __syncthreads();   // the ONLY barrier before the epilogue

    float s_part[16];
    #pragma unroll
    for (int i = 0; i < 16; ++i) s_part[i] = 0.0f;

    const int n_base = xc * 1600;
    // 100 n-tiles of 16 rows; wave w takes t = w, w+8, ... (13 or 12 tiles)
    for (int t = wave; t < 100; t += 8) {
        // load this wave's 16 mem rows: lane covers row n_base+t*16+c,
        // k-chunk quad*8 within each ks-32 slice (32 B = 2 float4)
        const char* rp = (const char*)mem
                       + (size_t)(n_base + t * 16 + c) * 512 + quad * 32;
        float4 ga[4], gb[4];
        #pragma unroll
        for (int ks = 0; ks < 4; ++ks) {
            ga[ks] = *(const float4*)(rp + ks * 128);
            gb[ks] = *(const float4*)(rp + ks * 128 + 16);
        }
        // pack to A-frags: lane L holds A[row=L&15][k=(L>>4)*8+j]
        bf16x8 af[4];
        #pragma unroll
        for (int ks = 0; ks < 4; ++ks) {
            uint4 pk;
            pk.x = pack_bf2(ga[ks].x, ga[ks].y); pk.y = pack_bf2(ga[ks].z, ga[ks].w);
            pk.z = pack_bf2(gb[ks].x, gb[ks].y); pk.w = pack_bf2(gb[ks].z, gb[ks].w);
            af[ks] = *(bf16x8*)&pk;
        }
        // m in 4 chunks of 64 (4 frags each) to keep acc at 16 regs
        #pragma unroll
        for (int ch = 0; ch < 4; ++ch) {
            f32x4 acc[4];
            #pragma unroll
            for (int f = 0; f < 4; ++f) acc[f] = (f32x4)(0.0f);
            #pragma unroll
            for (int ks = 0; ks < 4; ++ks)
                #pragma unroll
                for (int f = 0; f < 4; ++f) {
                    bf16x8 bf = *(const bf16x8*)&fLDS[((ch * 4 + f) * 4 + ks) * 64 + lane];
                    acc[f] = __builtin_amdgcn_mfma_f32_16x16x32_bf16(
                        af[ks], bf, acc[f], 0, 0, 0);
                }
            // exp2 + reduce over n (4 regs + 4 quads); col(L&15) = m stays local
            #pragma unroll
            for (int f = 0; f < 4; ++f) {
                float e = __builtin_amdgcn_exp2f(acc[f][0])
                        + __builtin_amdgcn_exp2f(acc[f][1])
                        + __builtin_amdgcn_exp2f(acc[f][2])
                        + __builtin_amdgcn_exp2f(acc[f][3]);
                e += __shfl_xor(e, 16, 64);
                e += __shfl_xor(e, 32, 64);
                s_part[ch * 4 + f] += e;
            }
        }
    }

    // epilogue: block-level reduce in LDS, then 256 global atomics
    #pragma unroll
    for (int i = 0; i < 16; ++i)
        if (quad == 0)
            atomicAdd(&S_lds[(i >> 2) * 64 + (i & 3) * 16 + c], s_part[i]);
    __syncthreads();
    if (tid < 256) atomicAdd(&S[m_base + tid], S_lds[tid]);
}

// ---- Kernel 3: pos logit + weighted mean ------------------------------------
__global__ void finalize_k(const unsigned short* __restrict__ featb,
                           const float* __restrict__ mem,
                           const int* __restrict__ labels,
                           const float* __restrict__ S,
                           float* __restrict__ out) {
    const int wave = threadIdx.x >> 6;
    const int lane = threadIdx.x & 63;
    const int b = blockIdx.x * 4 + wave;          // 256 blocks x 4 waves = 1024
    const int lab = labels[b];
    const float* mrow = mem + (size_t)lab * (4096 * 128);   // memory[lab][0][:]
    float fa = bf2f(featb[b * 128 + lane]);
    float fc = bf2f(featb[b * 128 + lane + 64]);
    float p = fa * mrow[lane] + fc * mrow[lane + 64];       // t_pos (log2 domain)
    #pragma unroll
    for (int m = 1; m < 64; m <<= 1) p += __shfl_xor(p, m, 64);
    if (lane == 0) {
        float w = (lab < 2) ? 1.3f : 1.0f;
        float v = w * LN2f * (log2f(S[b]) - p) * (1.0f / 1024.0f);
        atomicAdd(out, v);
    }
}

extern "C" void kernel_launch(void* const* d_in, const int* in_sizes, int n_in,
                              void* d_out, int out_size, void* d_ws, size_t ws_size,
                              hipStream_t stream) {
    const float* features = (const float*)d_in[0];
    const int*   labels   = (const int*)d_in[1];
    const float* memory   = (const float*)d_in[2];
    float* out = (float*)d_out;

    unsigned short* featb = (unsigned short*)d_ws;               // 256 KiB
    float* S = (float*)((char*)d_ws + 1024 * 128 * 2);           // 1024 floats

    normalize_feat<<<1024, 128, 0, stream>>>(features, featb, S, out);
    gemm_lse<<<dim3(128, 4), 512, 0, stream>>>(featb, memory, S);
    finalize_k<<<256, 256, 0, stream>>>(featb, memory, labels, S, out);
}